// Round 7
// baseline (64.011 us; speedup 1.0000x reference)
//
#include <hip/hip_runtime.h>

// SAN subtraction2: K=7, S=1, P=3, D=1, reflect pad.
// N=8, C=64, H=W=56 -> out [8,64,49,3136] fp32.
// out[nc, kk=i*7+j, oh*56+ow] = in2[nc, refl(oh+i-3), refl(ow+j-3)] - in1[nc,oh,ow]
//
// R7: block = one (nc,i) pair; block sweeps t=0..783 in 4 chunks of 256
// (last chunk = 16 threads). Each block's 7 j-plane write streams advance
// sequentially through one contiguous 86KB output region; reads are one
// 12.5KB in2 plane band + in1 plane, fully L1/L2-resident per block.
// Vectorized window loads kept from R6 (3x b128 + reflect fixups).

typedef float f4 __attribute__((ext_vector_type(4)));

#define KSZ 7
#define KK 49
#define HH 56
#define WW 56
#define L 3136   // 56*56
#define W4 14    // 56/4

__device__ __forceinline__ int refl56(int s) {
    s = s < 0 ? -s : s;
    return s >= 56 ? 110 - s : s;
}

__global__ __launch_bounds__(256) void sub2_kernel(
    const float* __restrict__ in1,
    const float* __restrict__ in2,
    float* __restrict__ out)
{
    // block -> (nc, i)
    int i  = blockIdx.x % KSZ;
    int nc = blockIdx.x / KSZ;

    const float* __restrict__ plane1 = in1 + (size_t)nc * L;
    const float* __restrict__ plane2 = in2 + (size_t)nc * L;
    float* __restrict__ outb = out + (size_t)(nc * KK + i * KSZ) * L;

    // sweep t = oh*14 + ow4 over [0,784) in 4 chunks of 256
#pragma unroll 1
    for (int t0 = 0; t0 < 784; t0 += 256) {
        int t = t0 + threadIdx.x;
        if (t >= 784) break;

        int oh  = t / W4;
        int ow4 = t % W4;
        int ow  = ow4 * 4;

        // query: one aligned float4
        const f4 q = *reinterpret_cast<const f4*>(plane1 + oh * WW + ow);

        // key row for this i (vertical reflect -> a real row)
        int rh = refl56(oh + i - 3);
        const float* __restrict__ row = plane2 + rh * WW;

        // 12-float window, 3 aligned b128 loads at clamped base word b
        int b = 4 * ow4 - 4;
        b = b < 0 ? 0 : (b > 44 ? 44 : b);
        const f4 p0 = *reinterpret_cast<const f4*>(row + b);
        const f4 p1 = *reinterpret_cast<const f4*>(row + b + 4);
        const f4 p2 = *reinterpret_cast<const f4*>(row + b + 8);
        float w[12] = {p0.x, p0.y, p0.z, p0.w,
                       p1.x, p1.y, p1.z, p1.w,
                       p2.x, p2.y, p2.z, p2.w};

        // v[d] = col (4*ow4 - 4 + d); interior: v[d] = w[d].
        // Edge fixups (reflect) for ow4==0 and ow4==13.
        bool e0  = (ow4 == 0);
        bool e13 = (ow4 == 13);
        float v[11];
        v[1]  = e0 ? w[3] : (e13 ? w[5]  : w[1]);
        v[2]  = e0 ? w[2] : (e13 ? w[6]  : w[2]);
        v[3]  = e0 ? w[1] : (e13 ? w[7]  : w[3]);
        v[4]  = e0 ? w[0] : (e13 ? w[8]  : w[4]);
        v[5]  = e0 ? w[1] : (e13 ? w[9]  : w[5]);
        v[6]  = e0 ? w[2] : (e13 ? w[10] : w[6]);
        v[7]  = e0 ? w[3] : (e13 ? w[11] : w[7]);
        v[8]  = e0 ? w[4] : (e13 ? w[10] : w[8]);
        v[9]  = e0 ? w[5] : w[9];
        v[10] = e0 ? w[6] : (e13 ? w[8]  : w[10]);

        float* outp = outb + oh * WW + ow;
#pragma unroll
        for (int j = 0; j < KSZ; ++j) {
            f4 r;
            r.x = v[j + 1] - q.x;
            r.y = v[j + 2] - q.y;
            r.z = v[j + 3] - q.z;
            r.w = v[j + 4] - q.w;
            *reinterpret_cast<f4*>(outp) = r;
            outp += L;
        }
    }
}

extern "C" void kernel_launch(void* const* d_in, const int* in_sizes, int n_in,
                              void* d_out, int out_size, void* d_ws, size_t ws_size,
                              hipStream_t stream) {
    const float* in1 = (const float*)d_in[0];
    const float* in2 = (const float*)d_in[1];
    float* out = (float*)d_out;

    // grid = 512 nc * 7 i = 3584 blocks; block sweeps its own 86KB region
    int grid = 512 * KSZ;
    sub2_kernel<<<grid, 256, 0, stream>>>(in1, in2, out);
}

// Round 8
// 63.493 us; speedup vs baseline: 1.0082x; 1.0082x over previous
//
#include <hip/hip_runtime.h>

// SAN subtraction2: K=7, S=1, P=3, D=1, reflect pad.
// N=8, C=64, H=W=56 -> out [8,64,49,3136] fp32.
// out[nc, kk=i*7+j, oh*56+ow] = in2[nc, refl(oh+i-3), refl(ow+j-3)] - in1[nc,oh,ow]
//
// R8: thread = (nc, oh, ow4) producing ALL 49 outputs, with ALL 22 loads
// (q + 7 rows x 3 b128 window loads) hoisted BEFORE the 49 stores.
// Rationale: CDNA shares one vmcnt between loads and stores, so R5/R7's
// load-after-store pattern falsely serialized on store completion. This
// keeps the R2/R6 "loads->stores->exit" property while amortizing index
// math 7x more and cutting fabric read traffic ~6x (99MB -> ~16MB).

typedef float f4 __attribute__((ext_vector_type(4)));

#define KSZ 7
#define KK 49
#define HH 56
#define WW 56
#define L 3136   // 56*56
#define W4 14    // 56/4

__device__ __forceinline__ int refl56(int s) {
    s = s < 0 ? -s : s;
    return s >= 56 ? 110 - s : s;
}

__global__ __launch_bounds__(256) void sub2_kernel(
    const float* __restrict__ in1,
    const float* __restrict__ in2,
    float* __restrict__ out,
    int total)
{
    int tid = blockIdx.x * blockDim.x + threadIdx.x;
    if (tid >= total) return;

    // tid = nc*784 + t,  t = oh*14 + ow4
    int t   = tid % 784;
    int nc  = tid / 784;
    int oh  = t / W4;
    int ow4 = t % W4;
    int ow  = ow4 * 4;

    const float* __restrict__ plane2 = in2 + (size_t)nc * L;

    // query pixel block (1 load)
    const f4 q = *reinterpret_cast<const f4*>(in1 + (size_t)nc * L + oh * WW + ow);

    // clamped aligned window base (word index), same for all rows
    int b = 4 * ow4 - 4;
    b = b < 0 ? 0 : (b > 44 ? 44 : b);

    // ALL 21 window loads issued up front (3 aligned b128 per reflected row)
    f4 p[KSZ][3];
#pragma unroll
    for (int i = 0; i < KSZ; ++i) {
        int rh = refl56(oh + i - 3);
        const float* __restrict__ row = plane2 + rh * WW + b;
        p[i][0] = *reinterpret_cast<const f4*>(row);
        p[i][1] = *reinterpret_cast<const f4*>(row + 4);
        p[i][2] = *reinterpret_cast<const f4*>(row + 8);
    }

    bool e0  = (ow4 == 0);
    bool e13 = (ow4 == 13);
    float* __restrict__ outb = out + ((size_t)nc * KK * L + oh * WW + ow);

    // 49 stores, no loads after any store -> no vmcnt false-wait
#pragma unroll
    for (int i = 0; i < KSZ; ++i) {
        float w[12] = {p[i][0].x, p[i][0].y, p[i][0].z, p[i][0].w,
                       p[i][1].x, p[i][1].y, p[i][1].z, p[i][1].w,
                       p[i][2].x, p[i][2].y, p[i][2].z, p[i][2].w};
        // v[d] = col(4*ow4 + d - 4); interior v[d]=w[d]; edge reflect fixups
        float v[11];
        v[1]  = e0 ? w[3] : (e13 ? w[5]  : w[1]);
        v[2]  = e0 ? w[2] : (e13 ? w[6]  : w[2]);
        v[3]  = e0 ? w[1] : (e13 ? w[7]  : w[3]);
        v[4]  = e0 ? w[0] : (e13 ? w[8]  : w[4]);
        v[5]  = e0 ? w[1] : (e13 ? w[9]  : w[5]);
        v[6]  = e0 ? w[2] : (e13 ? w[10] : w[6]);
        v[7]  = e0 ? w[3] : (e13 ? w[11] : w[7]);
        v[8]  = e0 ? w[4] : (e13 ? w[10] : w[8]);
        v[9]  = e0 ? w[5] : w[9];
        v[10] = e0 ? w[6] : (e13 ? w[8]  : w[10]);

        float* outp = outb + (size_t)i * KSZ * L;
#pragma unroll
        for (int j = 0; j < KSZ; ++j) {
            f4 r;
            r.x = v[j + 1] - q.x;
            r.y = v[j + 2] - q.y;
            r.z = v[j + 3] - q.z;
            r.w = v[j + 4] - q.w;
            *reinterpret_cast<f4*>(outp) = r;
            outp += L;
        }
    }
}

extern "C" void kernel_launch(void* const* d_in, const int* in_sizes, int n_in,
                              void* d_out, int out_size, void* d_ws, size_t ws_size,
                              hipStream_t stream) {
    const float* in1 = (const float*)d_in[0];
    const float* in2 = (const float*)d_in[1];
    float* out = (float*)d_out;

    // threads = 512 nc * 784 (oh,ow4) = 401,408 ; grid = 1568 blocks
    int total = 512 * 784;
    int block = 256;
    int grid = (total + block - 1) / block;
    sub2_kernel<<<grid, block, 0, stream>>>(in1, in2, out, total);
}

// Round 9
// 62.181 us; speedup vs baseline: 1.0294x; 1.0211x over previous
//
#include <hip/hip_runtime.h>

// SAN subtraction2: K=7, S=1, P=3, D=1, reflect pad.
// N=8, C=64, H=W=56 -> out [8,64,49,3136] fp32.
// out[nc, kk=i*7+j, 4t] = in2[nc, refl(oh+i-3), refl(ow+j-3)] - in1[nc, 4t]
//
// R9: window reads moved OFF the VMEM pipe. Block = (nc, half-plane):
// stage full 12.5KB in2 plane in LDS (3 f4 loads/thread), then per (t,i)
// read the 12-float window via 3 ds_read_b128 (LDS pipe / lgkmcnt) and
// issue 7 global stores. VMEM issue drops 0.80 -> ~0.55 instr/cyc/CU
// (theory: TA-port issue ~0.7/cyc is the binding limit; fill=0.69).

typedef float f4 __attribute__((ext_vector_type(4)));

#define KSZ 7
#define KK 49
#define HH 56
#define WW 56
#define L 3136   // 56*56
#define W4 14    // 56/4

__device__ __forceinline__ int refl56(int s) {
    s = s < 0 ? -s : s;
    return s >= 56 ? 110 - s : s;
}

__global__ __launch_bounds__(256) void sub2_kernel(
    const float* __restrict__ in1,
    const float* __restrict__ in2,
    float* __restrict__ out)
{
    __shared__ alignas(16) float lds2[L];

    // block -> (nc, half): half-plane split keeps 4 blocks/CU resident
    int half = blockIdx.x & 1;
    int nc   = blockIdx.x >> 1;

    const float* __restrict__ plane1 = in1 + (size_t)nc * L;
    const float* __restrict__ plane2 = in2 + (size_t)nc * L;
    float* __restrict__ outb = out + (size_t)nc * KK * L;

    // stage full in2 plane: 784 f4 loads spread over 256 threads
    for (int idx = threadIdx.x; idx < 784; idx += 256) {
        *reinterpret_cast<f4*>(lds2 + 4 * idx) =
            *reinterpret_cast<const f4*>(plane2 + 4 * idx);
    }
    __syncthreads();

    int t0 = half * 392;   // t in [t0, t0+392)
#pragma unroll 1
    for (int tt = 0; tt < 392; tt += 256) {
        if (tt + (int)threadIdx.x >= 392) break;
        int t = t0 + tt + threadIdx.x;

        int oh  = t / W4;
        int ow4 = t % W4;

        // query: one aligned f4 global load per 49 outputs (addr = 4t)
        const f4 q = *reinterpret_cast<const f4*>(plane1 + 4 * t);

        // clamped aligned window base (word index)
        int b = 4 * ow4 - 4;
        b = b < 0 ? 0 : (b > 44 ? 44 : b);
        bool e0  = (ow4 == 0);
        bool e13 = (ow4 == 13);

        float* outp0 = outb + 4 * t;

#pragma unroll
        for (int i = 0; i < KSZ; ++i) {
            int rh = refl56(oh + i - 3);
            const float* __restrict__ row = lds2 + rh * WW + b;
            // 3 aligned ds_read_b128 (LDS pipe, not VMEM)
            const f4 p0 = *reinterpret_cast<const f4*>(row);
            const f4 p1 = *reinterpret_cast<const f4*>(row + 4);
            const f4 p2 = *reinterpret_cast<const f4*>(row + 8);
            float w[12] = {p0.x, p0.y, p0.z, p0.w,
                           p1.x, p1.y, p1.z, p1.w,
                           p2.x, p2.y, p2.z, p2.w};
            // v[d] = col(4*ow4 + d - 4); interior v[d]=w[d]; edge reflect
            float v[11];
            v[1]  = e0 ? w[3] : (e13 ? w[5]  : w[1]);
            v[2]  = e0 ? w[2] : (e13 ? w[6]  : w[2]);
            v[3]  = e0 ? w[1] : (e13 ? w[7]  : w[3]);
            v[4]  = e0 ? w[0] : (e13 ? w[8]  : w[4]);
            v[5]  = e0 ? w[1] : (e13 ? w[9]  : w[5]);
            v[6]  = e0 ? w[2] : (e13 ? w[10] : w[6]);
            v[7]  = e0 ? w[3] : (e13 ? w[11] : w[7]);
            v[8]  = e0 ? w[4] : (e13 ? w[10] : w[8]);
            v[9]  = e0 ? w[5] : w[9];
            v[10] = e0 ? w[6] : (e13 ? w[8]  : w[10]);

            float* outp = outp0 + (size_t)i * KSZ * L;
#pragma unroll
            for (int j = 0; j < KSZ; ++j) {
                f4 r;
                r.x = v[j + 1] - q.x;
                r.y = v[j + 2] - q.y;
                r.z = v[j + 3] - q.z;
                r.w = v[j + 4] - q.w;
                *reinterpret_cast<f4*>(outp) = r;
                outp += L;
            }
        }
    }
}

extern "C" void kernel_launch(void* const* d_in, const int* in_sizes, int n_in,
                              void* d_out, int out_size, void* d_ws, size_t ws_size,
                              hipStream_t stream) {
    const float* in1 = (const float*)d_in[0];
    const float* in2 = (const float*)d_in[1];
    float* out = (float*)d_out;

    // grid = 512 nc * 2 halves = 1024 blocks x 256 threads
    int grid = 512 * 2;
    sub2_kernel<<<grid, 256, 0, stream>>>(in1, in2, out);
}